// Round 1
// baseline (867.552 us; speedup 1.0000x reference)
//
#include <hip/hip_runtime.h>
#include <math.h>

// Problem constants (fixed by the reference)
#define B_   4
#define C_   256
#define CQK  32
#define N_   4096

// Attention tiling
#define TQ   64   // query rows per block
#define TM   32   // kv rows per chunk

// LDS strides (floats) — chosen for bank-conflict avoidance + 16B alignment
#define QS_STR 36   // 36*4B = 144B, 16B-aligned rows; stride%32=4 -> 2-way max on b128
#define KS_STR 36
#define VS_STR 257  // odd stride: (j + c)%32 distinct -> conflict-free b32
#define PS_STR 68   // 68*4B = 272B, 16B-aligned rows

// -------------------- projection: out[b][o][n] = bias[o] + sum_c W[o][c] x[b][c][n]
__global__ __launch_bounds__(256) void proj_kernel(
    const float* __restrict__ x, const float* __restrict__ W,
    const float* __restrict__ bias, float* __restrict__ out, int Cout)
{
    const int n  = blockIdx.x * 256 + threadIdx.x;
    const int og = blockIdx.y;   // group of 8 output channels
    const int b  = blockIdx.z;

    const float* xb = x + (size_t)b * C_ * N_ + n;
    const float* wr = W + (size_t)(og * 8) * C_;

    float acc[8];
#pragma unroll
    for (int j = 0; j < 8; ++j) acc[j] = bias[og * 8 + j];

    for (int c = 0; c < C_; ++c) {
        float xv = xb[(size_t)c * N_];
#pragma unroll
        for (int j = 0; j < 8; ++j) acc[j] = fmaf(wr[j * C_ + c], xv, acc[j]);
    }

    float* ob = out + ((size_t)b * Cout + og * 8) * N_ + n;
#pragma unroll
    for (int j = 0; j < 8; ++j) ob[(size_t)j * N_] = acc[j];
}

// -------------------- flash attention + residual
__global__ __launch_bounds__(256) void attn_kernel(
    const float* __restrict__ x, const float* __restrict__ q,
    const float* __restrict__ k, const float* __restrict__ v,
    float* __restrict__ out)
{
    __shared__ __align__(16) float qs[TQ * QS_STR];   //  9216 B
    __shared__ __align__(16) float ks[TM * KS_STR];   //  4608 B
    __shared__ __align__(16) float vs[TM * VS_STR];   // 32896 B
    __shared__ __align__(16) float ps[TM * PS_STR];   //  8704 B
    __shared__ float pmax[TQ * 4];
    __shared__ float psum[TQ * 4];
    __shared__ float mstate[TQ];
    __shared__ float lstate[TQ];
    __shared__ float alph[TQ];

    const int t  = threadIdx.x;
    const int b  = blockIdx.y;
    const int q0 = blockIdx.x * TQ;

    // score-phase mapping: thread computes S[i][j] for i = s_i0..s_i0+3, j = jj*16 + s_jl
    const int s_i0 = (t >> 4) * 4;
    const int s_jl = t & 15;
    // PV-phase mapping: thread owns i = p_ti*8 + ii (ii<8), c = p_tc + 32*qq (qq<8)
    const int p_ti = t >> 5;
    const int p_tc = t & 31;

    if (t < TQ) { mstate[t] = -INFINITY; lstate[t] = 0.0f; }

    // stage q rows for this block: qs[i][c] = q[b][c][q0+i]
    {
        const int i = t & 63, c0 = t >> 6;  // c0 in 0..3
        const float* qbp = q + (size_t)(b * CQK) * N_ + q0 + i;
#pragma unroll
        for (int w = 0; w < 8; ++w) {
            int c = c0 + 4 * w;
            qs[i * QS_STR + c] = qbp[(size_t)c * N_];
        }
    }

    float O[8][8];
#pragma unroll
    for (int ii = 0; ii < 8; ++ii)
#pragma unroll
        for (int qq = 0; qq < 8; ++qq) O[ii][qq] = 0.0f;

    __syncthreads();

    for (int m0 = 0; m0 < N_; m0 += TM) {
        // ---- stage k,v chunk
        {
            const int j = t & 31, c0 = t >> 5;  // c0 in 0..7
            const float* kb = k + (size_t)(b * CQK) * N_ + m0 + j;
#pragma unroll
            for (int w = 0; w < 4; ++w) {
                int c = c0 + 8 * w;
                ks[j * KS_STR + c] = kb[(size_t)c * N_];
            }
            const float* vb = v + (size_t)(b * C_) * N_ + m0 + j;
#pragma unroll
            for (int w = 0; w < 32; ++w) {
                int c = c0 + 8 * w;
                vs[j * VS_STR + c] = vb[(size_t)c * N_];
            }
        }
        __syncthreads();

        // ---- scores: S[i][j] = sum_c q[i][c] k[j][c]
        float sc[4][2];
#pragma unroll
        for (int ii = 0; ii < 4; ++ii)
#pragma unroll
            for (int jj = 0; jj < 2; ++jj) sc[ii][jj] = 0.0f;

#pragma unroll
        for (int c4 = 0; c4 < 8; ++c4) {
            float4 qv[4], kv[2];
#pragma unroll
            for (int ii = 0; ii < 4; ++ii)
                qv[ii] = *(const float4*)&qs[(s_i0 + ii) * QS_STR + c4 * 4];
#pragma unroll
            for (int jj = 0; jj < 2; ++jj)
                kv[jj] = *(const float4*)&ks[(jj * 16 + s_jl) * KS_STR + c4 * 4];
#pragma unroll
            for (int ii = 0; ii < 4; ++ii)
#pragma unroll
                for (int jj = 0; jj < 2; ++jj) {
                    sc[ii][jj] = fmaf(qv[ii].x, kv[jj].x, sc[ii][jj]);
                    sc[ii][jj] = fmaf(qv[ii].y, kv[jj].y, sc[ii][jj]);
                    sc[ii][jj] = fmaf(qv[ii].z, kv[jj].z, sc[ii][jj]);
                    sc[ii][jj] = fmaf(qv[ii].w, kv[jj].w, sc[ii][jj]);
                }
        }
#pragma unroll
        for (int jj = 0; jj < 2; ++jj)
#pragma unroll
            for (int ii = 0; ii < 4; ++ii)
                ps[(jj * 16 + s_jl) * PS_STR + s_i0 + ii] = sc[ii][jj];
        __syncthreads();

        // ---- online softmax: partial row max
        {
            const int i = t >> 2, jq = t & 3;
            float mx = -INFINITY;
#pragma unroll
            for (int jj = 0; jj < 8; ++jj)
                mx = fmaxf(mx, ps[(jq * 8 + jj) * PS_STR + i]);
            pmax[i * 4 + jq] = mx;
        }
        __syncthreads();
        if (t < TQ) {
            float m_old = mstate[t];
            float m_row = fmaxf(fmaxf(pmax[t * 4 + 0], pmax[t * 4 + 1]),
                                fmaxf(pmax[t * 4 + 2], pmax[t * 4 + 3]));
            float m_new = fmaxf(m_old, m_row);
            mstate[t] = m_new;
            alph[t]   = __expf(m_old - m_new);
        }
        __syncthreads();
        // exponentiate in place, partial sums
        {
            const int i = t >> 2, jq = t & 3;
            const float mn = mstate[i];
            float sm = 0.0f;
#pragma unroll
            for (int jj = 0; jj < 8; ++jj) {
                int idx = (jq * 8 + jj) * PS_STR + i;
                float p = __expf(ps[idx] - mn);
                ps[idx] = p;
                sm += p;
            }
            psum[i * 4 + jq] = sm;
        }
        __syncthreads();
        if (t < TQ) {
            lstate[t] = lstate[t] * alph[t] +
                        (psum[t * 4 + 0] + psum[t * 4 + 1] +
                         psum[t * 4 + 2] + psum[t * 4 + 3]);
        }

        // ---- PV accumulate: O[i][c] = O*alpha + sum_j p[i][j] v[c][j]
        float a8[8];
#pragma unroll
        for (int ii = 0; ii < 8; ++ii) a8[ii] = alph[p_ti * 8 + ii];
#pragma unroll
        for (int ii = 0; ii < 8; ++ii)
#pragma unroll
            for (int qq = 0; qq < 8; ++qq) O[ii][qq] *= a8[ii];

        for (int j = 0; j < TM; ++j) {
            float4 pA = *(const float4*)&ps[j * PS_STR + p_ti * 8];
            float4 pB = *(const float4*)&ps[j * PS_STR + p_ti * 8 + 4];
            float pp[8] = {pA.x, pA.y, pA.z, pA.w, pB.x, pB.y, pB.z, pB.w};
            float vv[8];
#pragma unroll
            for (int qq = 0; qq < 8; ++qq)
                vv[qq] = vs[j * VS_STR + p_tc + 32 * qq];
#pragma unroll
            for (int ii = 0; ii < 8; ++ii)
#pragma unroll
                for (int qq = 0; qq < 8; ++qq)
                    O[ii][qq] = fmaf(pp[ii], vv[qq], O[ii][qq]);
        }
        __syncthreads();
    }

    // ---- epilogue: out = x + O / l
    float linv[8];
#pragma unroll
    for (int ii = 0; ii < 8; ++ii) linv[ii] = 1.0f / lstate[p_ti * 8 + ii];

#pragma unroll
    for (int qq = 0; qq < 8; ++qq) {
        const int c = p_tc + 32 * qq;
        const size_t base = ((size_t)(b * C_) + c) * N_ + q0 + p_ti * 8;
        float4 xa = *(const float4*)&x[base];
        float4 xb = *(const float4*)&x[base + 4];
        float4 oa, ob;
        oa.x = xa.x + O[0][qq] * linv[0];
        oa.y = xa.y + O[1][qq] * linv[1];
        oa.z = xa.z + O[2][qq] * linv[2];
        oa.w = xa.w + O[3][qq] * linv[3];
        ob.x = xb.x + O[4][qq] * linv[4];
        ob.y = xb.y + O[5][qq] * linv[5];
        ob.z = xb.z + O[6][qq] * linv[6];
        ob.w = xb.w + O[7][qq] * linv[7];
        *(float4*)&out[base]     = oa;
        *(float4*)&out[base + 4] = ob;
    }
}

extern "C" void kernel_launch(void* const* d_in, const int* in_sizes, int n_in,
                              void* d_out, int out_size, void* d_ws, size_t ws_size,
                              hipStream_t stream) {
    const float* x  = (const float*)d_in[0];
    const float* Wq = (const float*)d_in[1];
    const float* bq = (const float*)d_in[2];
    const float* Wk = (const float*)d_in[3];
    const float* bk = (const float*)d_in[4];
    const float* Wv = (const float*)d_in[5];
    const float* bv = (const float*)d_in[6];
    float* out = (float*)d_out;

    float* ws = (float*)d_ws;
    float* qb = ws;                                    // [B][CQK][N]  2 MB
    float* kb = ws + (size_t)B_ * CQK * N_;            // [B][CQK][N]  2 MB
    float* vb = ws + 2 * (size_t)B_ * CQK * N_;        // [B][C][N]   16 MB

    proj_kernel<<<dim3(N_ / 256, CQK / 8, B_), 256, 0, stream>>>(x, Wq, bq, qb, CQK);
    proj_kernel<<<dim3(N_ / 256, CQK / 8, B_), 256, 0, stream>>>(x, Wk, bk, kb, CQK);
    proj_kernel<<<dim3(N_ / 256, C_ / 8, B_), 256, 0, stream>>>(x, Wv, bv, vb, C_);
    attn_kernel<<<dim3(N_ / TQ, B_), 256, 0, stream>>>(x, qb, kb, vb, out);
}

// Round 2
// 271.090 us; speedup vs baseline: 3.2002x; 3.2002x over previous
//
#include <hip/hip_runtime.h>
#include <math.h>

#define B_   4
#define C_   256
#define CQK  32
#define N_   4096
#define TQ   64
#define TM   64

typedef __attribute__((ext_vector_type(8))) short short8;
typedef __attribute__((ext_vector_type(4))) float f32x4;
typedef __attribute__((ext_vector_type(2))) unsigned int uint2v;

__device__ __forceinline__ unsigned short f2bf(float f) {
    unsigned u = __builtin_bit_cast(unsigned, f);
    u += 0x7fffu + ((u >> 16) & 1u);
    return (unsigned short)(u >> 16);
}

// ---------- q,k projection (bf16 out, layout [b][n][c]) ----------
// grid (N/256, 4, B): by 0,1 -> q (channels 0-15,16-31); by 2,3 -> k
__global__ __launch_bounds__(256) void proj_qk(
    const float* __restrict__ x,
    const float* __restrict__ Wq, const float* __restrict__ bq,
    const float* __restrict__ Wk, const float* __restrict__ bk,
    unsigned short* __restrict__ qb, unsigned short* __restrict__ kb)
{
    const int n = blockIdx.x * 256 + threadIdx.x;
    const int b = blockIdx.z;
    const int sel = blockIdx.y >> 1;
    const int og  = (blockIdx.y & 1) * 16;
    const float* Wm = sel ? Wk : Wq;
    const float* bm = sel ? bk : bq;
    unsigned short* ob = sel ? kb : qb;

    float acc[16];
#pragma unroll
    for (int j = 0; j < 16; ++j) acc[j] = bm[og + j];

    const float* xb = x + (size_t)b * C_ * N_ + n;
#pragma unroll 4
    for (int c = 0; c < C_; ++c) {
        const float xv = xb[(size_t)c * N_];
#pragma unroll
        for (int j = 0; j < 16; ++j)
            acc[j] = fmaf(Wm[(og + j) * C_ + c], xv, acc[j]);
    }

    short8 u0, u1;
#pragma unroll
    for (int j = 0; j < 8; ++j) {
        u0[j] = (short)f2bf(acc[j]);
        u1[j] = (short)f2bf(acc[8 + j]);
    }
    unsigned short* op = ob + ((size_t)(b * N_) + n) * 32 + og;
    *(short8*)op = u0;
    *(short8*)(op + 8) = u1;
}

// ---------- v projection (bf16 out, layout [b][c][n]) ----------
// grid (N/256, C/16, B)
__global__ __launch_bounds__(256) void proj_v(
    const float* __restrict__ x,
    const float* __restrict__ Wv, const float* __restrict__ bv,
    unsigned short* __restrict__ vb)
{
    const int n  = blockIdx.x * 256 + threadIdx.x;
    const int b  = blockIdx.z;
    const int og = blockIdx.y * 16;

    float acc[16];
#pragma unroll
    for (int j = 0; j < 16; ++j) acc[j] = bv[og + j];

    const float* xb = x + (size_t)b * C_ * N_ + n;
#pragma unroll 4
    for (int c = 0; c < C_; ++c) {
        const float xv = xb[(size_t)c * N_];
#pragma unroll
        for (int j = 0; j < 16; ++j)
            acc[j] = fmaf(Wv[(og + j) * C_ + c], xv, acc[j]);
    }
#pragma unroll
    for (int j = 0; j < 16; ++j)
        vb[((size_t)(b * C_) + og + j) * N_ + n] = f2bf(acc[j]);
}

// ---------- flash attention, MFMA, S^T orientation ----------
// grid (N/TQ, B), 256 threads (4 waves)
__global__ __launch_bounds__(256) void attn_kernel(
    const float* __restrict__ x,
    const unsigned short* __restrict__ qg,
    const unsigned short* __restrict__ kg,
    const unsigned short* __restrict__ vg,
    float* __restrict__ out)
{
    __shared__ __align__(16) unsigned short qs[64 * 40];   // [q][c]  pad->40
    __shared__ __align__(16) unsigned short ks[64 * 40];   // [kv][c] pad->40
    __shared__ __align__(16) unsigned short vs[256 * 64];  // [c][kv] XOR-swizzled
    __shared__ __align__(16) unsigned short ps[64 * 72];   // [q][kv] pad->72
    __shared__ float alph[64];
    __shared__ float ls[64];

    const int t    = threadIdx.x;
    const int w    = t >> 6;
    const int lane = t & 63;
    const int quad = lane >> 4;
    const int c16  = lane & 15;
    const int b    = blockIdx.y;
    const int q0   = blockIdx.x * TQ;
    const int qw   = w >> 1, cw = w & 1;

    // stage Q tile (once)
    {
        const int row = t >> 2, seg = t & 3;
        const short8 v = *(const short8*)(qg + ((size_t)(b * N_) + q0 + row) * 32 + seg * 8);
        *(short8*)&qs[row * 40 + seg * 8] = v;
    }

    // prefetch K/V chunk 0 into registers
    short8 kpre, vpre[8];
    {
        const int row = t >> 2, seg = t & 3;
        kpre = *(const short8*)(kg + ((size_t)(b * N_) + row) * 32 + seg * 8);
        const int vc = t >> 3, vch = t & 7;
#pragma unroll
        for (int p = 0; p < 8; ++p)
            vpre[p] = *(const short8*)(vg + ((size_t)(b * C_) + vc + 32 * p) * N_ + vch * 8);
    }

    f32x4 O[2][8];
#pragma unroll
    for (int rt = 0; rt < 2; ++rt)
#pragma unroll
        for (int ch = 0; ch < 8; ++ch) O[rt][ch] = (f32x4){0.f, 0.f, 0.f, 0.f};

    float m_run = -INFINITY, l_run = 0.0f;

#pragma unroll 1
    for (int it = 0; it < N_ / TM; ++it) {
        const int m0 = it * TM;
        __syncthreads();  // prev PV reads done
        {   // registers -> LDS
            const int row = t >> 2, seg = t & 3;
            *(short8*)&ks[row * 40 + seg * 8] = kpre;
            const int vc0 = t >> 3, vch = t & 7;
#pragma unroll
            for (int p = 0; p < 8; ++p) {
                const int c = vc0 + 32 * p;
                *(short8*)&vs[c * 64 + 8 * (vch ^ (c & 7))] = vpre[p];
            }
        }
        __syncthreads();
        if (it < N_ / TM - 1) {  // prefetch next chunk
            const int m1 = m0 + TM;
            const int row = t >> 2, seg = t & 3;
            kpre = *(const short8*)(kg + ((size_t)(b * N_) + m1 + row) * 32 + seg * 8);
            const int vc = t >> 3, vch = t & 7;
#pragma unroll
            for (int p = 0; p < 8; ++p)
                vpre[p] = *(const short8*)(vg + ((size_t)(b * C_) + vc + 32 * p) * N_ + m1 + vch * 8);
        }

        // ---- S^T = K.Q^T : wave w owns q cols 16w..16w+15
        const short8 bqf = *(const short8*)&qs[(16 * w + c16) * 40 + quad * 8];
        f32x4 sf[4];
#pragma unroll
        for (int f = 0; f < 4; ++f) {
            const short8 akf = *(const short8*)&ks[(16 * f + c16) * 40 + quad * 8];
            const f32x4 z = {0.f, 0.f, 0.f, 0.f};
            sf[f] = __builtin_amdgcn_mfma_f32_16x16x32_bf16(akf, bqf, z, 0, 0, 0);
        }
        // ---- online softmax over kv (rows of S^T)
        float mx = -INFINITY;
#pragma unroll
        for (int f = 0; f < 4; ++f)
#pragma unroll
            for (int r = 0; r < 4; ++r) mx = fmaxf(mx, sf[f][r]);
        mx = fmaxf(mx, __shfl_xor(mx, 16));
        mx = fmaxf(mx, __shfl_xor(mx, 32));
        const float m_new = fmaxf(m_run, mx);
        const float al = __expf(m_run - m_new);
        m_run = m_new;
        float rs = 0.f;
        float p4[4][4];
#pragma unroll
        for (int f = 0; f < 4; ++f)
#pragma unroll
            for (int r = 0; r < 4; ++r) {
                p4[f][r] = __expf(sf[f][r] - m_new);
                rs += p4[f][r];
            }
        rs += __shfl_xor(rs, 16);
        rs += __shfl_xor(rs, 32);
        l_run = l_run * al + rs;
        if (quad == 0) alph[16 * w + c16] = al;
        // P^T -> LDS (bf16), rows q, cols kv; lane's 16 vals are 4 runs of 4
#pragma unroll
        for (int f = 0; f < 4; ++f) {
            uint2v u;
            u.x = (unsigned)f2bf(p4[f][0]) | ((unsigned)f2bf(p4[f][1]) << 16);
            u.y = (unsigned)f2bf(p4[f][2]) | ((unsigned)f2bf(p4[f][3]) << 16);
            *(uint2v*)&ps[(16 * w + c16) * 72 + 16 * f + 4 * quad] = u;
        }
        __syncthreads();

        // ---- PV: O^T[c][q] += V^T[c][kv] . P^T[kv][q]; wave (qw,cw)
        const float a0 = alph[32 * qw + c16];
        const float a1 = alph[32 * qw + 16 + c16];
#pragma unroll
        for (int ch = 0; ch < 8; ++ch)
#pragma unroll
            for (int r = 0; r < 4; ++r) { O[0][ch][r] *= a0; O[1][ch][r] *= a1; }

        short8 bp[2][2];
#pragma unroll
        for (int rt = 0; rt < 2; ++rt)
#pragma unroll
            for (int h = 0; h < 2; ++h)
                bp[rt][h] = *(const short8*)&ps[(32 * qw + 16 * rt + c16) * 72 + 32 * h + 8 * quad];

#pragma unroll
        for (int ch = 0; ch < 8; ++ch) {
            const int c = 128 * cw + 16 * ch + c16;
#pragma unroll
            for (int h = 0; h < 2; ++h) {
                const short8 av = *(const short8*)&vs[c * 64 + 8 * ((4 * h + quad) ^ (c & 7))];
                O[0][ch] = __builtin_amdgcn_mfma_f32_16x16x32_bf16(av, bp[0][h], O[0][ch], 0, 0, 0);
                O[1][ch] = __builtin_amdgcn_mfma_f32_16x16x32_bf16(av, bp[1][h], O[1][ch], 0, 0, 0);
            }
        }
    }

    if (quad == 0) ls[16 * w + c16] = l_run;
    __syncthreads();

    const float li0 = 1.0f / ls[32 * qw + c16];
    const float li1 = 1.0f / ls[32 * qw + 16 + c16];
#pragma unroll
    for (int rt = 0; rt < 2; ++rt) {
        const float li = rt ? li1 : li0;
        const int n = q0 + 32 * qw + 16 * rt + c16;
#pragma unroll
        for (int ch = 0; ch < 8; ++ch) {
#pragma unroll
            for (int r = 0; r < 4; ++r) {
                const int c = 128 * cw + 16 * ch + 4 * quad + r;
                const size_t idx = ((size_t)(b * C_) + c) * N_ + n;
                out[idx] = x[idx] + O[rt][ch][r] * li;
            }
        }
    }
}

extern "C" void kernel_launch(void* const* d_in, const int* in_sizes, int n_in,
                              void* d_out, int out_size, void* d_ws, size_t ws_size,
                              hipStream_t stream) {
    const float* x  = (const float*)d_in[0];
    const float* Wq = (const float*)d_in[1];
    const float* bq = (const float*)d_in[2];
    const float* Wk = (const float*)d_in[3];
    const float* bk = (const float*)d_in[4];
    const float* Wv = (const float*)d_in[5];
    const float* bv = (const float*)d_in[6];
    float* out = (float*)d_out;

    unsigned short* ws16 = (unsigned short*)d_ws;
    unsigned short* qb = ws16;                               // [B][N][32] bf16, 1 MB
    unsigned short* kb = qb + (size_t)B_ * N_ * 32;          // [B][N][32] bf16, 1 MB
    unsigned short* vb = kb + (size_t)B_ * N_ * 32;          // [B][C][N]  bf16, 8 MB

    proj_qk<<<dim3(N_ / 256, 4, B_), 256, 0, stream>>>(x, Wq, bq, Wk, bk, qb, kb);
    proj_v <<<dim3(N_ / 256, C_ / 16, B_), 256, 0, stream>>>(x, Wv, bv, vb);
    attn_kernel<<<dim3(N_ / TQ, B_), 256, 0, stream>>>(x, qb, kb, vb, out);
}

// Round 3
// 176.853 us; speedup vs baseline: 4.9055x; 1.5329x over previous
//
#include <hip/hip_runtime.h>
#include <math.h>

#define B_   4
#define C_   256
#define CQK  32
#define N_   4096
#define TQ   32
#define TM   64

typedef __attribute__((ext_vector_type(8))) short short8;
typedef __attribute__((ext_vector_type(4))) short short4v;
typedef __attribute__((ext_vector_type(4))) float f32x4;
typedef __attribute__((ext_vector_type(2))) unsigned int uint2v;

__device__ __forceinline__ unsigned short f2bf(float f) {
    unsigned u = __builtin_bit_cast(unsigned, f);
    u += 0x7fffu + ((u >> 16) & 1u);
    return (unsigned short)(u >> 16);
}

// ---------- convert weights to bf16 [320][256] + fp32 bias[320] ----------
__global__ __launch_bounds__(256) void cvt_w(
    const float* __restrict__ Wq, const float* __restrict__ bq,
    const float* __restrict__ Wk, const float* __restrict__ bk,
    const float* __restrict__ Wv, const float* __restrict__ bv,
    unsigned short* __restrict__ wbf, float* __restrict__ biasf)
{
    const int r = blockIdx.x;   // 0..319
    const int t = threadIdx.x;
    const float* src = (r < 32) ? (Wq + r * C_)
                     : (r < 64) ? (Wk + (r - 32) * C_)
                                : (Wv + (r - 64) * C_);
    wbf[r * C_ + t] = f2bf(src[t]);
    if (t == 0)
        biasf[r] = (r < 32) ? bq[r] : (r < 64) ? bk[r - 32] : bv[r - 64];
}

// ---------- fused qkv projection GEMM: M=320, K=256, N=64 per block ----------
// q,k -> [b][n][32] bf16 ; v -> [b][c][n] bf16
__global__ __launch_bounds__(256) void proj_qkv(
    const float* __restrict__ x, const unsigned short* __restrict__ wbf,
    const float* __restrict__ biasf,
    unsigned short* __restrict__ qb, unsigned short* __restrict__ kb,
    unsigned short* __restrict__ vb)
{
    __shared__ __align__(16) unsigned short xs[64 * 136];  // [n][c_half] pad->136

    const int t    = threadIdx.x;
    const int w    = t >> 6;
    const int lane = t & 63;
    const int quad = lane >> 4;
    const int c16  = lane & 15;
    const int n0   = blockIdx.x * 64;
    const int b    = blockIdx.y;

    f32x4 acc[5][4];
#pragma unroll
    for (int i = 0; i < 5; ++i)
#pragma unroll
        for (int nt = 0; nt < 4; ++nt) acc[i][nt] = (f32x4){0.f, 0.f, 0.f, 0.f};

#pragma unroll
    for (int half = 0; half < 2; ++half) {
        __syncthreads();
        // stage x[128c x 64n] transposed -> xs[n][c], bf16
#pragma unroll
        for (int pass = 0; pass < 8; ++pass) {
            const int c  = 128 * half + pass * 16 + (t >> 4);
            const int nq = (t & 15) * 4;
            const f32x4 xv = *(const f32x4*)&x[((size_t)(b * C_) + c) * N_ + n0 + nq];
            const int cl = c - 128 * half;
            xs[(nq + 0) * 136 + cl] = f2bf(xv.x);
            xs[(nq + 1) * 136 + cl] = f2bf(xv.y);
            xs[(nq + 2) * 136 + cl] = f2bf(xv.z);
            xs[(nq + 3) * 136 + cl] = f2bf(xv.w);
        }
        __syncthreads();
#pragma unroll
        for (int ks = 0; ks < 4; ++ks) {
            short8 af[5], bf[4];
#pragma unroll
            for (int i = 0; i < 5; ++i) {
                const int o = (5 * w + i) * 16 + c16;
                af[i] = *(const short8*)&wbf[o * C_ + half * 128 + ks * 32 + quad * 8];
            }
#pragma unroll
            for (int nt = 0; nt < 4; ++nt)
                bf[nt] = *(const short8*)&xs[(16 * nt + c16) * 136 + ks * 32 + quad * 8];
#pragma unroll
            for (int i = 0; i < 5; ++i)
#pragma unroll
                for (int nt = 0; nt < 4; ++nt)
                    acc[i][nt] = __builtin_amdgcn_mfma_f32_16x16x32_bf16(af[i], bf[nt], acc[i][nt], 0, 0, 0);
        }
    }

    // epilogue
#pragma unroll
    for (int i = 0; i < 5; ++i) {
        const int OT = 5 * w + i;
        const int obase = OT * 16 + 4 * quad;
        const f32x4 bv4 = *(const f32x4*)&biasf[obase];
#pragma unroll
        for (int nt = 0; nt < 4; ++nt) {
            const int n = n0 + 16 * nt + c16;
            float vals[4];
#pragma unroll
            for (int r = 0; r < 4; ++r) vals[r] = acc[i][nt][r] + bv4[r];
            if (OT < 4) {  // q (OT 0,1) or k (OT 2,3): [b][n][32]
                unsigned short* dst = (OT < 2) ? qb : kb;
                const int o = obase - ((OT < 2) ? 0 : 32);
                short4v pk;
#pragma unroll
                for (int r = 0; r < 4; ++r) pk[r] = (short)f2bf(vals[r]);
                *(short4v*)&dst[((size_t)(b * N_) + n) * 32 + o] = pk;
            } else {       // v: [b][c][n]
#pragma unroll
                for (int r = 0; r < 4; ++r) {
                    const int c = obase + r - 64;
                    vb[((size_t)(b * C_) + c) * N_ + n] = f2bf(vals[r]);
                }
            }
        }
    }
}

// ---------- flash attention (no-max softmax), MFMA, S^T orientation ----------
// grid (N/TQ=128, B), 256 threads (4 waves)
__global__ __launch_bounds__(256) void attn_kernel(
    const float* __restrict__ x,
    const unsigned short* __restrict__ qg,
    const unsigned short* __restrict__ kg,
    const unsigned short* __restrict__ vg,
    float* __restrict__ out)
{
    __shared__ __align__(16) unsigned short qs[TQ * 40];   // [q][c]
    __shared__ __align__(16) unsigned short ks[TM * 40];   // [kv][c]
    __shared__ __align__(16) unsigned short vs[256 * 64];  // [c][kv] XOR-swizzled
    __shared__ __align__(16) unsigned short ps[TQ * 72];   // [q][kv]
    __shared__ float ls[2 * TQ];

    const int t    = threadIdx.x;
    const int w    = t >> 6;
    const int lane = t & 63;
    const int quad = lane >> 4;
    const int c16  = lane & 15;
    const int b    = blockIdx.y;
    const int q0   = blockIdx.x * TQ;
    const int qh   = w & 1;   // q-half for S phase
    const int kh   = w >> 1;  // kv-half for S phase

    // stage Q tile (once): 32 rows x 4 segs
    if (t < 128) {
        const int row = t >> 2, seg = t & 3;
        *(short8*)&qs[row * 40 + seg * 8] =
            *(const short8*)(qg + ((size_t)(b * N_) + q0 + row) * 32 + seg * 8);
    }

    // prefetch K/V chunk 0
    short8 kpre, vpre[8];
    {
        const int row = t >> 2, seg = t & 3;
        kpre = *(const short8*)(kg + ((size_t)(b * N_) + row) * 32 + seg * 8);
        const int vc = t >> 3, vch = t & 7;
#pragma unroll
        for (int p = 0; p < 8; ++p)
            vpre[p] = *(const short8*)(vg + ((size_t)(b * C_) + vc + 32 * p) * N_ + vch * 8);
    }

    f32x4 O[4][2];
#pragma unroll
    for (int ct = 0; ct < 4; ++ct)
#pragma unroll
        for (int qt = 0; qt < 2; ++qt) O[ct][qt] = (f32x4){0.f, 0.f, 0.f, 0.f};

    float l_run = 0.0f;

#pragma unroll 1
    for (int it = 0; it < N_ / TM; ++it) {
        __syncthreads();  // prev PV reads done
        {   // registers -> LDS
            const int row = t >> 2, seg = t & 3;
            *(short8*)&ks[row * 40 + seg * 8] = kpre;
            const int vc0 = t >> 3, vch = t & 7;
#pragma unroll
            for (int p = 0; p < 8; ++p) {
                const int c = vc0 + 32 * p;
                *(short8*)&vs[c * 64 + 8 * (vch ^ (c & 7))] = vpre[p];
            }
        }
        __syncthreads();
        if (it < N_ / TM - 1) {  // prefetch next chunk
            const int m1 = (it + 1) * TM;
            const int row = t >> 2, seg = t & 3;
            kpre = *(const short8*)(kg + ((size_t)(b * N_) + m1 + row) * 32 + seg * 8);
            const int vc = t >> 3, vch = t & 7;
#pragma unroll
            for (int p = 0; p < 8; ++p)
                vpre[p] = *(const short8*)(vg + ((size_t)(b * C_) + vc + 32 * p) * N_ + m1 + vch * 8);
        }

        // ---- S^T = K.Q^T : wave covers kv 32*kh..+31, q 16*qh..+15
        const short8 bqf = *(const short8*)&qs[(16 * qh + c16) * 40 + quad * 8];
        float rs = 0.f;
#pragma unroll
        for (int f = 0; f < 2; ++f) {
            const short8 akf = *(const short8*)&ks[(32 * kh + 16 * f + c16) * 40 + quad * 8];
            const f32x4 z = {0.f, 0.f, 0.f, 0.f};
            const f32x4 sf = __builtin_amdgcn_mfma_f32_16x16x32_bf16(akf, bqf, z, 0, 0, 0);
            float p4[4];
#pragma unroll
            for (int r = 0; r < 4; ++r) { p4[r] = __expf(sf[r]); rs += p4[r]; }
            uint2v u;
            u.x = (unsigned)f2bf(p4[0]) | ((unsigned)f2bf(p4[1]) << 16);
            u.y = (unsigned)f2bf(p4[2]) | ((unsigned)f2bf(p4[3]) << 16);
            *(uint2v*)&ps[(16 * qh + c16) * 72 + 32 * kh + 16 * f + 4 * quad] = u;
        }
        rs += __shfl_xor(rs, 16);
        rs += __shfl_xor(rs, 32);
        l_run += rs;
        __syncthreads();

        // ---- PV: O^T[c][q] += V^T[c][kv] . P^T[kv][q]; wave owns c 64w..64w+63
#pragma unroll
        for (int s = 0; s < 2; ++s) {
            const short8 bp0 = *(const short8*)&ps[(c16) * 72 + 32 * s + 8 * quad];
            const short8 bp1 = *(const short8*)&ps[(16 + c16) * 72 + 32 * s + 8 * quad];
#pragma unroll
            for (int ct = 0; ct < 4; ++ct) {
                const int c = 64 * w + 16 * ct + c16;
                const short8 av = *(const short8*)&vs[c * 64 + 8 * ((4 * s + quad) ^ (c & 7))];
                O[ct][0] = __builtin_amdgcn_mfma_f32_16x16x32_bf16(av, bp0, O[ct][0], 0, 0, 0);
                O[ct][1] = __builtin_amdgcn_mfma_f32_16x16x32_bf16(av, bp1, O[ct][1], 0, 0, 0);
            }
        }
    }

    if (quad == 0) ls[kh * TQ + 16 * qh + c16] = l_run;
    __syncthreads();

#pragma unroll
    for (int qt = 0; qt < 2; ++qt) {
        const int q = 16 * qt + c16;
        const float li = 1.0f / (ls[q] + ls[TQ + q]);
        const int n = q0 + q;
#pragma unroll
        for (int ct = 0; ct < 4; ++ct) {
#pragma unroll
            for (int r = 0; r < 4; ++r) {
                const int c = 64 * w + 16 * ct + 4 * quad + r;
                const size_t idx = ((size_t)(b * C_) + c) * N_ + n;
                out[idx] = x[idx] + O[ct][qt][r] * li;
            }
        }
    }
}

extern "C" void kernel_launch(void* const* d_in, const int* in_sizes, int n_in,
                              void* d_out, int out_size, void* d_ws, size_t ws_size,
                              hipStream_t stream) {
    const float* x  = (const float*)d_in[0];
    const float* Wq = (const float*)d_in[1];
    const float* bq = (const float*)d_in[2];
    const float* Wk = (const float*)d_in[3];
    const float* bk = (const float*)d_in[4];
    const float* Wv = (const float*)d_in[5];
    const float* bv = (const float*)d_in[6];
    float* out = (float*)d_out;

    unsigned short* ws16 = (unsigned short*)d_ws;
    unsigned short* qb  = ws16;                              // [B][N][32]  1 MB
    unsigned short* kb  = qb + (size_t)B_ * N_ * 32;         // [B][N][32]  1 MB
    unsigned short* vb  = kb + (size_t)B_ * N_ * 32;         // [B][C][N]   8 MB
    unsigned short* wbf = vb + (size_t)B_ * C_ * N_;         // [320][256] bf16
    float* biasf = (float*)(wbf + 320 * C_);                 // [320] fp32

    cvt_w<<<dim3(320), 256, 0, stream>>>(Wq, bq, Wk, bk, Wv, bv, wbf, biasf);
    proj_qkv<<<dim3(N_ / 64, B_), 256, 0, stream>>>(x, wbf, biasf, qb, kb, vb);
    attn_kernel<<<dim3(N_ / TQ, B_), 256, 0, stream>>>(x, qb, kb, vb, out);
}